// Round 2
// baseline (1422.024 us; speedup 1.0000x reference)
//
#include <hip/hip_runtime.h>
#include <hip/hip_bf16.h>

#define EPS  1e-5f
#define CNTF 409600.0f          // N*T*V
#define XDP_ELEMS 6553600       // 16384 * 400 per layer

// ---------------- K1: Gram of x (64x64) + channel sums, once ----------------
__global__ __launch_bounds__(256) void k_gram(const float* __restrict__ x,
                                              float* __restrict__ Gx,
                                              float* __restrict__ sx)
{
    __shared__ float xs[64][129];
    const int tid = threadIdx.x;
    const int i4 = tid >> 4, j4 = tid & 15;
    float g[16];
#pragma unroll
    for (int r = 0; r < 16; r++) g[r] = 0.f;
    float sxp = 0.f;

    for (int tt = 0; tt < 4; tt++) {
        __syncthreads();
        int p0 = blockIdx.x * 512 + tt * 128;
        int n = p0 / 3200, pb = p0 - n * 3200;
        const float* xb = x + n * 204800 + pb;
        for (int i = tid; i < 8192; i += 256) {
            int c = i >> 7, j = i & 127;
            xs[c][j] = xb[c * 3200 + j];
        }
        __syncthreads();
        for (int p = 0; p < 128; p++) {
            float a0 = xs[4*i4+0][p], a1 = xs[4*i4+1][p];
            float a2 = xs[4*i4+2][p], a3 = xs[4*i4+3][p];
            float b0 = xs[4*j4+0][p], b1 = xs[4*j4+1][p];
            float b2 = xs[4*j4+2][p], b3 = xs[4*j4+3][p];
            g[0]  += a0*b0; g[1]  += a0*b1; g[2]  += a0*b2; g[3]  += a0*b3;
            g[4]  += a1*b0; g[5]  += a1*b1; g[6]  += a1*b2; g[7]  += a1*b3;
            g[8]  += a2*b0; g[9]  += a2*b1; g[10] += a2*b2; g[11] += a2*b3;
            g[12] += a3*b0; g[13] += a3*b1; g[14] += a3*b2; g[15] += a3*b3;
        }
        if (tid < 64) {
            for (int j = 0; j < 128; j++) sxp += xs[tid][j];
        }
    }
#pragma unroll
    for (int r = 0; r < 4; r++)
#pragma unroll
        for (int cc = 0; cc < 4; cc++)
            atomicAdd(&Gx[(4*i4 + r) * 64 + 4*j4 + cc], g[r*4 + cc]);
    if (tid < 64) atomicAdd(&sx[tid], sxp);
}

// ---------- K2: finalize down-BN affines for all 3 layers (tiny) ----------
__global__ __launch_bounds__(192) void k_fin_down(
    const float* __restrict__ Wd, const float* __restrict__ bd,
    const float* __restrict__ gd, const float* __restrict__ betad,
    const float* __restrict__ Gx, const float* __restrict__ sx,
    float* __restrict__ AC)     // A[48] then C[48]
{
    const int tid = threadIdx.x;
    const int lo = tid >> 2, q = tid & 3;
    const int l = lo / 16, o = lo - l * 16;
    const float* w = Wd + l * 1024 + o * 64;
    float syp = 0.f, e2p = 0.f;
    for (int c = q * 16; c < q * 16 + 16; c++) {
        float wc = w[c];
        syp += wc * sx[c];
        float rowp = 0.f;
        for (int c2 = 0; c2 < 64; c2++) rowp += w[c2] * Gx[c * 64 + c2];
        e2p += wc * rowp;
    }
    syp += __shfl_down(syp, 2, 4); syp += __shfl_down(syp, 1, 4);
    e2p += __shfl_down(e2p, 2, 4); e2p += __shfl_down(e2p, 1, 4);
    if (q == 0) {
        float my  = syp * (1.f / CNTF);
        float var = e2p * (1.f / CNTF) - my * my;   // bias cancels in var
        float a   = gd[l * 16 + o] * rsqrtf(var + EPS);
        AC[lo]      = a;
        AC[48 + lo] = betad[l * 16 + o] - a * my;   // fold: relu(a*(Wx) + C)
    }
}

// ------- K3: conv_down for ALL 3 layers, x read once, bf16 xd out -------
__global__ __launch_bounds__(256) void k_down3(
    const float* __restrict__ x, const float* __restrict__ Wd,
    const float* __restrict__ AC, __hip_bfloat16* __restrict__ xdp)
{
    __shared__ float Wt[64][48];
    __shared__ float As[48], Cs[48];
    const int tid = threadIdx.x;
    for (int i = tid; i < 3072; i += 256) {
        int c = i / 48, k = i - c * 48;
        int l = k / 16, o = k - l * 16;
        Wt[c][k] = Wd[l * 1024 + o * 64 + c];
    }
    if (tid < 48) { As[tid] = AC[tid]; Cs[tid] = AC[48 + tid]; }
    __syncthreads();

    const int base = (blockIdx.x * 256 + tid) * 2;
    const int n = base / 3200, pb = base - n * 3200;
    const float* xb = x + n * 204800 + pb;
    float acc[2][48];
#pragma unroll
    for (int k = 0; k < 48; k++) { acc[0][k] = 0.f; acc[1][k] = 0.f; }
    for (int c = 0; c < 64; c++) {
        float2 xv = *(const float2*)&xb[c * 3200];
#pragma unroll
        for (int k = 0; k < 48; k++) {
            float wv = Wt[c][k];
            acc[0][k] += wv * xv.x;
            acc[1][k] += wv * xv.y;
        }
    }
#pragma unroll
    for (int j = 0; j < 2; j++) {
        int p = base + j;
        int nt = p / 25, u = p - nt * 25;
#pragma unroll
        for (int l = 0; l < 3; l++)
#pragma unroll
            for (int o = 0; o < 16; o++) {
                float val = fmaxf(As[l*16+o] * acc[j][l*16+o] + Cs[l*16+o], 0.f);
                xdp[(size_t)l * XDP_ELEMS + (size_t)nt * 400 + o * 25 + u] =
                    __float2bfloat16(val);
            }
    }
}

// ------- K4: z-stats for all 3 layers (o-paired, b128 LDS reads) -------
__global__ __launch_bounds__(320) void k_zstats3(
    const __hip_bfloat16* __restrict__ xdp, const float* __restrict__ PA,
    const float* __restrict__ Wsub, const float* __restrict__ bsub,
    float* __restrict__ stq)    // [3][160]
{
    __shared__ float PAs[3500];       // [s][v:25][u:28 padded]
    __shared__ float xds[3616];       // [8][452]: c*28+u padded, stride 452
    __shared__ float bins[160];
    const int tid = threadIdx.x;
    for (int i = tid; i < 3616; i += 320) xds[i] = 0.f;   // pads stay 0

    const int pp = tid / 40;
    const int q  = tid - pp * 40;
    const int s  = q >> 3, oo = q & 7;
    const int nt0 = blockIdx.x * 16;

    for (int l = 0; l < 3; l++) {
        __syncthreads();   // prev layer fully done (incl. bins flush by owner)
        for (int i = tid; i < 3500; i += 320) {
            int sN = i / 700, r = i - sN * 700;
            int v = r / 28, u = r - v * 28;
            PAs[i] = (u < 25) ? PA[(size_t)l * 3125 + (sN * 25 + v) * 25 + u] : 0.f;
        }
        if (tid < 160) bins[tid] = 0.f;
        float w0[16], w1[16];
#pragma unroll
        for (int c = 0; c < 16; c++) {
            w0[c] = Wsub[l * 1280 + (s * 16 + oo) * 16 + c];
            w1[c] = Wsub[l * 1280 + (s * 16 + oo + 8) * 16 + c];
        }
        const float b0 = bsub[l * 80 + s * 16 + oo];
        const float b1 = bsub[l * 80 + s * 16 + oo + 8];
        float s0 = 0.f, q0 = 0.f, s1 = 0.f, q1 = 0.f;

        for (int it = 0; it < 2; it++) {
            __syncthreads();
            const int ntb = nt0 + it * 8;
            for (int i = tid; i < 3200; i += 320) {
                int lp = i / 400, r = i - lp * 400;
                int c = r / 25, u = r - c * 25;
                xds[lp * 452 + c * 28 + u] = __bfloat162float(
                    xdp[(size_t)l * XDP_ELEMS + (size_t)(ntb + lp) * 400 + r]);
            }
            __syncthreads();

            float e0[28], e1[28];
#pragma unroll
            for (int u = 0; u < 28; u++) { e0[u] = 0.f; e1[u] = 0.f; }
#pragma unroll
            for (int c = 0; c < 16; c++) {
                float wc0 = w0[c], wc1 = w1[c];
#pragma unroll
                for (int u4 = 0; u4 < 7; u4++) {
                    const float4 xc = *(const float4*)&xds[pp * 452 + c * 28 + u4 * 4];
                    e0[4*u4+0] += wc0 * xc.x; e0[4*u4+1] += wc0 * xc.y;
                    e0[4*u4+2] += wc0 * xc.z; e0[4*u4+3] += wc0 * xc.w;
                    e1[4*u4+0] += wc1 * xc.x; e1[4*u4+1] += wc1 * xc.y;
                    e1[4*u4+2] += wc1 * xc.z; e1[4*u4+3] += wc1 * xc.w;
                }
            }
            for (int v = 0; v < 25; v++) {
                float z0 = b0, z1 = b1;
#pragma unroll
                for (int u4 = 0; u4 < 7; u4++) {
                    const float4 pa = *(const float4*)&PAs[s * 700 + v * 28 + u4 * 4];
                    z0 += pa.x*e0[4*u4] + pa.y*e0[4*u4+1] + pa.z*e0[4*u4+2] + pa.w*e0[4*u4+3];
                    z1 += pa.x*e1[4*u4] + pa.y*e1[4*u4+1] + pa.z*e1[4*u4+2] + pa.w*e1[4*u4+3];
                }
                s0 += z0; q0 += z0 * z0;
                s1 += z1; q1 += z1 * z1;
            }
        }
        atomicAdd(&bins[s * 16 + oo],      s0);
        atomicAdd(&bins[80 + s * 16 + oo], q0);
        atomicAdd(&bins[s * 16 + oo + 8],      s1);
        atomicAdd(&bins[80 + s * 16 + oo + 8], q1);
        __syncthreads();
        if (tid < 160) atomicAdd(&stq[l * 160 + tid], bins[tid]);
    }
}

// ------- K5: fused 3-layer output + acc stats, coalesced transpose write -------
__global__ __launch_bounds__(256) void k_out3(
    const __hip_bfloat16* __restrict__ xdp, const float* __restrict__ PA,
    const float* __restrict__ Wsub, const float* __restrict__ bsub,
    const float* __restrict__ gs, const float* __restrict__ betas,
    const float* __restrict__ stq, float* __restrict__ stout,
    float* __restrict__ out)
{
    __shared__ float PAs[3500];
    __shared__ float xds[3616];       // [8][452]
    __shared__ float Wss[1280];
    __shared__ float AS[240], CS[240];
    __shared__ float tile[32][201];
    const int tid = threadIdx.x;

    if (tid < 240) {
        int l = tid / 80, ch = tid - l * 80;
        float m   = stq[l * 160 + ch] * (1.f / CNTF);
        float var = stq[l * 160 + 80 + ch] * (1.f / CNTF) - m * m;
        float a   = gs[l * 80 + ch] * rsqrtf(var + EPS);
        AS[tid] = a;
        CS[tid] = betas[l * 80 + ch] + a * (bsub[l * 80 + ch] - m);
    }
    for (int i = tid; i < 3616; i += 256) xds[i] = 0.f;

    const int nt0 = blockIdx.x * 8;
    const int n = nt0 >> 7, t0 = nt0 & 127;
    const int pp = tid / 25, v = tid - pp * 25;
    const bool active = tid < 200;

    float outacc[64];
#pragma unroll
    for (int k = 0; k < 64; k++) outacc[k] = 0.f;

    for (int l = 0; l < 3; l++) {
        __syncthreads();
        for (int i = tid; i < 3500; i += 256) {
            int sN = i / 700, r = i - sN * 700;
            int vv = r / 28, u = r - vv * 28;
            PAs[i] = (u < 25) ? PA[(size_t)l * 3125 + (sN * 25 + vv) * 25 + u] : 0.f;
        }
        for (int i = tid; i < 1280; i += 256) Wss[i] = Wsub[l * 1280 + i];
        for (int i = tid; i < 3200; i += 256) {
            int lp = i / 400, r = i - lp * 400;
            int c = r / 25, u = r - c * 25;
            xds[lp * 452 + c * 28 + u] = __bfloat162float(
                xdp[(size_t)l * XDP_ELEMS + (size_t)(nt0 + lp) * 400 + r]);
        }
        __syncthreads();

        if (active) {
            float w[5][16];
#pragma unroll
            for (int s = 0; s < 5; s++)
#pragma unroll
                for (int c = 0; c < 16; c++) w[s][c] = 0.f;
#pragma unroll
            for (int u4 = 0; u4 < 7; u4++) {
                float4 pa[5];
#pragma unroll
                for (int s = 0; s < 5; s++)
                    pa[s] = *(const float4*)&PAs[s * 700 + v * 28 + u4 * 4];
#pragma unroll
                for (int c = 0; c < 16; c++) {
                    const float4 xc = *(const float4*)&xds[pp * 452 + c * 28 + u4 * 4];
#pragma unroll
                    for (int s = 0; s < 5; s++)
                        w[s][c] += pa[s].x*xc.x + pa[s].y*xc.y + pa[s].z*xc.z + pa[s].w*xc.w;
                }
            }
            float z0[16];
#pragma unroll
            for (int s = 0; s < 5; s++)
#pragma unroll
                for (int o = 0; o < 16; o++) {
                    float z = 0.f;
#pragma unroll
                    for (int j = 0; j < 4; j++) {
                        const float4 ww = *(const float4*)&Wss[(s * 16 + o) * 16 + j * 4];
                        z += ww.x*w[s][4*j] + ww.y*w[s][4*j+1] + ww.z*w[s][4*j+2] + ww.w*w[s][4*j+3];
                    }
                    float zb = AS[l * 80 + s * 16 + o] * z + CS[l * 80 + s * 16 + o];
                    if (s == 0) z0[o] = zb;
                    else        outacc[(s - 1) * 16 + o] += zb + z0[o];
                }
        }
    }

    // transpose + coalesced write + per-k stats, two 32-channel passes
#pragma unroll
    for (int h = 0; h < 2; h++) {
        __syncthreads();
        if (active) {
#pragma unroll
            for (int kk = 0; kk < 32; kk++) tile[kk][tid] = outacc[h * 32 + kk];
        }
        __syncthreads();
        for (int i = tid; i < 6400; i += 256) {
            int kk = i / 200, p = i - kk * 200;
            out[n * 204800 + (h * 32 + kk) * 3200 + t0 * 25 + p] = tile[kk][p];
        }
        {
            int kk = tid >> 3, c8 = tid & 7;
            float sv = 0.f, qv = 0.f;
            for (int j = 0; j < 25; j++) {
                float xv = tile[kk][c8 * 25 + j];
                sv += xv; qv += xv * xv;
            }
            sv += __shfl_down(sv, 4, 8); sv += __shfl_down(sv, 2, 8); sv += __shfl_down(sv, 1, 8);
            qv += __shfl_down(qv, 4, 8); qv += __shfl_down(qv, 2, 8); qv += __shfl_down(qv, 1, 8);
            if ((tid & 7) == 0) {
                atomicAdd(&stout[h * 32 + kk], sv);
                atomicAdd(&stout[64 + h * 32 + kk], qv);
            }
        }
    }
}

// ---- K6: out = relu(bn(acc) + x), in place on d_out, float4 ----
__global__ __launch_bounds__(256) void k_final(
    const float* __restrict__ x, const float* __restrict__ go,
    const float* __restrict__ bo, const float* __restrict__ stout,
    float* __restrict__ out)
{
    __shared__ float ao[64], co[64];
    const int tid = threadIdx.x;
    if (tid < 64) {
        float m   = stout[tid] * (1.f / CNTF);
        float var = stout[64 + tid] * (1.f / CNTF) - m * m;
        float a   = go[tid] * rsqrtf(var + EPS);
        ao[tid] = a; co[tid] = bo[tid] - m * a;
    }
    __syncthreads();
    const float4* x4 = (const float4*)x;
    float4* o4 = (float4*)out;
    for (int i = blockIdx.x * 256 + tid; i < 6553600; i += gridDim.x * 256) {
        int k = (i / 800) & 63;
        float a = ao[k], c = co[k];
        float4 vo = o4[i], vx = x4[i];
        vo.x = fmaxf(fmaf(a, vo.x, c) + vx.x, 0.f);
        vo.y = fmaxf(fmaf(a, vo.y, c) + vx.y, 0.f);
        vo.z = fmaxf(fmaf(a, vo.z, c) + vx.z, 0.f);
        vo.w = fmaxf(fmaf(a, vo.w, c) + vx.w, 0.f);
        o4[i] = vo;
    }
}

extern "C" void kernel_launch(void* const* d_in, const int* in_sizes, int n_in,
                              void* d_out, int out_size, void* d_ws, size_t ws_size,
                              hipStream_t stream)
{
    const float* x     = (const float*)d_in[0];
    const float* PA    = (const float*)d_in[1];
    const float* Wd    = (const float*)d_in[2];
    const float* bd    = (const float*)d_in[3];
    const float* gd    = (const float*)d_in[4];
    const float* betad = (const float*)d_in[5];
    const float* Wsub  = (const float*)d_in[6];
    const float* bsub  = (const float*)d_in[7];
    const float* gsub  = (const float*)d_in[8];
    const float* betas = (const float*)d_in[9];
    const float* gout  = (const float*)d_in[10];
    const float* betao = (const float*)d_in[11];
    float* out = (float*)d_out;

    __hip_bfloat16* xdp = (__hip_bfloat16*)d_ws;             // 3*6,553,600 bf16 = 39.3 MB
    float* st    = (float*)((char*)d_ws + (size_t)3 * XDP_ELEMS * 2);
    float* Gx    = st;            // 4096
    float* sx    = st + 4096;     // 64
    float* AC    = st + 4160;     // 96
    float* stq   = st + 4256;     // 480
    float* stout = st + 4736;     // 128

    hipMemsetAsync(st, 0, 4864 * sizeof(float), stream);

    k_gram    <<<800,  256, 0, stream>>>(x, Gx, sx);
    k_fin_down<<<1,    192, 0, stream>>>(Wd, bd, gd, betad, Gx, sx, AC);
    k_down3   <<<800,  256, 0, stream>>>(x, Wd, AC, xdp);
    k_zstats3 <<<1024, 320, 0, stream>>>(xdp, PA, Wsub, bsub, stq);
    k_out3    <<<2048, 256, 0, stream>>>(xdp, PA, Wsub, bsub, gsub, betas, stq, stout, out);
    k_final   <<<2048, 256, 0, stream>>>(x, gout, betao, stout, out);
}